// Round 2
// baseline (572.375 us; speedup 1.0000x reference)
//
#include <hip/hip_runtime.h>
#include <hip/hip_bf16.h>

typedef __attribute__((ext_vector_type(8))) short short8;
typedef __attribute__((ext_vector_type(4))) float floatx4;

#define GLOBAL_AS __attribute__((address_space(1)))
#define LDS_AS    __attribute__((address_space(3)))

__device__ __forceinline__ unsigned short f2bf_rne(float x) {
  unsigned int u = __float_as_uint(x);
  u += 0x7fffu + ((u >> 16) & 1u);
  return (unsigned short)(u >> 16);
}

// ---------------- cast fp32 -> bf16 (8 elems/thread) ----------------
__global__ void cast_f32_bf16_kernel(const float* __restrict__ in,
                                     unsigned short* __restrict__ out, int n8) {
  int i = blockIdx.x * 256 + threadIdx.x;
  if (i >= n8) return;
  const float4* p = (const float4*)in;
  float4 v0 = p[2 * i], v1 = p[2 * i + 1];
  short8 o;
  o[0] = (short)f2bf_rne(v0.x); o[1] = (short)f2bf_rne(v0.y);
  o[2] = (short)f2bf_rne(v0.z); o[3] = (short)f2bf_rne(v0.w);
  o[4] = (short)f2bf_rne(v1.x); o[5] = (short)f2bf_rne(v1.y);
  o[6] = (short)f2bf_rne(v1.z); o[7] = (short)f2bf_rne(v1.w);
  *(short8*)(out + 8 * (size_t)i) = o;
}

// ---------------- transpose + cast: in[R][C] fp32 -> out[C][R] bf16 ----------------
__global__ void transpose_cast_kernel(const float* __restrict__ in,
                                      unsigned short* __restrict__ out, int R, int C) {
  __shared__ unsigned short tile[32][33];
  int tx = threadIdx.x & 31, ty = threadIdx.x >> 5;
  int r0 = blockIdx.y * 32, c0 = blockIdx.x * 32;
#pragma unroll
  for (int j = 0; j < 32; j += 8)
    tile[ty + j][tx] = f2bf_rne(in[(size_t)(r0 + ty + j) * C + c0 + tx]);
  __syncthreads();
#pragma unroll
  for (int j = 0; j < 32; j += 8)
    out[(size_t)(c0 + ty + j) * R + r0 + tx] = tile[tx][ty + j];
}

// ---------------- small init / zero kernels ----------------
__global__ void zero4_kernel(float* __restrict__ p, int n4) {
  int i = blockIdx.x * 256 + threadIdx.x;
  if (i < n4) ((float4*)p)[i] = make_float4(0.f, 0.f, 0.f, 0.f);
}
__global__ void init_vec_kernel(const float* __restrict__ src, float* __restrict__ dst) {
  int i = blockIdx.x * 256 + threadIdx.x;
  dst[i] = src[i];
}
// broadcast bias1[1024] over 6272 rows (float4)
__global__ void bcast_bias_kernel(const float* __restrict__ bias1, float* __restrict__ dst) {
  int i = blockIdx.x * 256 + threadIdx.x;   // 1,605,632 float4s
  ((float4*)dst)[i] = ((const float4*)bias1)[i & 255];
}
__global__ void bias1_accum_kernel(const float* __restrict__ bg, const float* __restrict__ Gs,
                                   float* __restrict__ bias1) {
  int j = blockIdx.x * 256 + threadIdx.x;   // 0..1023
  int k0 = blockIdx.y * 256;
  float acc = 0.f;
  for (int k = 0; k < 256; ++k) acc += bg[k0 + k] * Gs[(size_t)(k0 + k) * 1024 + j];
  atomicAdd(&bias1[j], acc);
}

// ---------------- dec_fea = s_t_hat @ Wdec + bdec (fp32) ----------------
__global__ void init_dec_kernel(const float* __restrict__ bdec, float* __restrict__ dec) {
  int i = blockIdx.x * 256 + threadIdx.x;   // 32768
  dec[i] = bdec[i & 1023];
}
__global__ void dec_accum_kernel(const float* __restrict__ sth, const float* __restrict__ Wdec,
                                 float* __restrict__ dec) {
  __shared__ float ss[32][128];
  const int tid = threadIdx.x;
  const int k0 = blockIdx.y * 128;
  for (int i = tid; i < 32 * 128; i += 256) {
    int bb = i >> 7, kk = i & 127;
    ss[bb][kk] = sth[bb * 1024 + k0 + kk];
  }
  __syncthreads();
  const int j = blockIdx.x * 256 + tid;
  float acc[32];
#pragma unroll
  for (int b = 0; b < 32; ++b) acc[b] = 0.f;
  for (int kk = 0; kk < 128; ++kk) {
    float w = Wdec[(size_t)(k0 + kk) * 1024 + j];
#pragma unroll
    for (int b = 0; b < 32; ++b) acc[b] += ss[b][kk] * w;
  }
  for (int b = 0; b < 32; ++b) atomicAdd(&dec[b * 1024 + j], acc[b]);
}

// ---------------- split-K GEMM: C[M,N] += A[M,K-chunk] @ BT^T  (atomicAdd epilogue) ----------
// blockIdx.z selects the K-chunk. C must be pre-initialized (zero or bias).
__global__ __launch_bounds__(256, 4) void gemm_bt_atomic_kernel(
    const unsigned short* __restrict__ A, const unsigned short* __restrict__ BT,
    float* __restrict__ C, int M, int N, int K, int kchunk) {
  __shared__ unsigned short lds_a[128 * 32];
  __shared__ unsigned short lds_b[128 * 32];
  const int tid = threadIdx.x;
  const int lane = tid & 63;
  const int wave = tid >> 6;
  const int wm = wave >> 1, wn = wave & 1;
  const int quad = lane >> 4, col = lane & 15;
  const int m0 = blockIdx.y * 128, n0 = blockIdx.x * 128;
  const int kbase = blockIdx.z * kchunk;

  floatx4 acc[4][4] = {};

  const int srow = tid >> 2;           // 0..63
  const int skoff = (tid & 3) * 8;     // 0,8,16,24
  const unsigned short* a_ptr = A + (size_t)(m0 + srow) * K + kbase + skoff;
  const unsigned short* b_ptr = BT + (size_t)(n0 + srow) * K + kbase + skoff;
  const size_t rowskip = (size_t)64 * K;
  char* la_dst = (char*)lds_a + tid * 16;
  char* lb_dst = (char*)lds_b + tid * 16;

  for (int kt = 0; kt < kchunk; kt += 32) {
    __syncthreads();
    __builtin_amdgcn_global_load_lds((const GLOBAL_AS void*)(a_ptr), (LDS_AS void*)(la_dst), 16, 0, 0);
    __builtin_amdgcn_global_load_lds((const GLOBAL_AS void*)(a_ptr + rowskip), (LDS_AS void*)(la_dst + 4096), 16, 0, 0);
    __builtin_amdgcn_global_load_lds((const GLOBAL_AS void*)(b_ptr), (LDS_AS void*)(lb_dst), 16, 0, 0);
    __builtin_amdgcn_global_load_lds((const GLOBAL_AS void*)(b_ptr + rowskip), (LDS_AS void*)(lb_dst + 4096), 16, 0, 0);
    a_ptr += 32; b_ptr += 32;
    __syncthreads();
    short8 af[4], bf[4];
#pragma unroll
    for (int t = 0; t < 4; ++t) {
      af[t] = *(const short8*)((const char*)lds_a + (wm * 64 + t * 16 + col) * 64 + quad * 16);
      bf[t] = *(const short8*)((const char*)lds_b + (wn * 64 + t * 16 + col) * 64 + quad * 16);
    }
#pragma unroll
    for (int tm = 0; tm < 4; ++tm)
#pragma unroll
      for (int tn = 0; tn < 4; ++tn)
        acc[tm][tn] = __builtin_amdgcn_mfma_f32_16x16x32_bf16(af[tm], bf[tn], acc[tm][tn], 0, 0, 0);
  }

#pragma unroll
  for (int tm = 0; tm < 4; ++tm) {
    const int mg = m0 + wm * 64 + tm * 16 + quad * 4;
#pragma unroll
    for (int tn = 0; tn < 4; ++tn) {
      const int ng = n0 + wn * 64 + tn * 16 + col;
#pragma unroll
      for (int r = 0; r < 4; ++r)
        atomicAdd(&C[(size_t)(mg + r) * N + ng], acc[tm][tn][r]);
    }
  }
}

// ---------------- GEMM3 fused with scores: scores[row] += sum_j tanh(w+dec+cov)*v[j] -------
// w = A @ BT^T computed in registers, never materialized. scores pre-zeroed.
__global__ __launch_bounds__(256, 2) void gemm_scores_kernel(
    const unsigned short* __restrict__ A, const unsigned short* __restrict__ BT,
    const float* __restrict__ dec, const float* __restrict__ cov,
    const float* __restrict__ v, float* __restrict__ scores, int M, int N, int K) {
  __shared__ unsigned short lds_a[128 * 32];
  __shared__ unsigned short lds_b[128 * 32];
  const int tid = threadIdx.x;
  const int lane = tid & 63;
  const int wave = tid >> 6;
  const int wm = wave >> 1, wn = wave & 1;
  const int quad = lane >> 4, col = lane & 15;
  const int m0 = blockIdx.y * 128, n0 = blockIdx.x * 128;

  floatx4 acc[4][4] = {};

  const int srow = tid >> 2;
  const int skoff = (tid & 3) * 8;
  const unsigned short* a_ptr = A + (size_t)(m0 + srow) * K + skoff;
  const unsigned short* b_ptr = BT + (size_t)(n0 + srow) * K + skoff;
  const size_t rowskip = (size_t)64 * K;
  char* la_dst = (char*)lds_a + tid * 16;
  char* lb_dst = (char*)lds_b + tid * 16;

  for (int kt = 0; kt < K; kt += 32) {
    __syncthreads();
    __builtin_amdgcn_global_load_lds((const GLOBAL_AS void*)(a_ptr), (LDS_AS void*)(la_dst), 16, 0, 0);
    __builtin_amdgcn_global_load_lds((const GLOBAL_AS void*)(a_ptr + rowskip), (LDS_AS void*)(la_dst + 4096), 16, 0, 0);
    __builtin_amdgcn_global_load_lds((const GLOBAL_AS void*)(b_ptr), (LDS_AS void*)(lb_dst), 16, 0, 0);
    __builtin_amdgcn_global_load_lds((const GLOBAL_AS void*)(b_ptr + rowskip), (LDS_AS void*)(lb_dst + 4096), 16, 0, 0);
    a_ptr += 32; b_ptr += 32;
    __syncthreads();
    short8 af[4], bf[4];
#pragma unroll
    for (int t = 0; t < 4; ++t) {
      af[t] = *(const short8*)((const char*)lds_a + (wm * 64 + t * 16 + col) * 64 + quad * 16);
      bf[t] = *(const short8*)((const char*)lds_b + (wn * 64 + t * 16 + col) * 64 + quad * 16);
    }
#pragma unroll
    for (int tm = 0; tm < 4; ++tm)
#pragma unroll
      for (int tn = 0; tn < 4; ++tn)
        acc[tm][tn] = __builtin_amdgcn_mfma_f32_16x16x32_bf16(af[tm], bf[tn], acc[tm][tn], 0, 0, 0);
  }

  // epilogue: per-row partial tanh-dot over this block's 128-column slice
  const int n_base = n0 + wn * 64;
  float vv[4];
#pragma unroll
  for (int tn = 0; tn < 4; ++tn) vv[tn] = v[n_base + tn * 16 + col];
#pragma unroll
  for (int tm = 0; tm < 4; ++tm) {
#pragma unroll
    for (int r = 0; r < 4; ++r) {
      const int row = m0 + wm * 64 + tm * 16 + quad * 4 + r;
      const int b = row / 196;
      const float cw = cov[row];
      const float* dr = dec + b * 1024 + n_base;
      float s = 0.f;
#pragma unroll
      for (int tn = 0; tn < 4; ++tn)
        s += tanhf(acc[tm][tn][r] + dr[tn * 16 + col] + cw) * vv[tn];
      s += __shfl_xor(s, 1, 64);
      s += __shfl_xor(s, 2, 64);
      s += __shfl_xor(s, 4, 64);
      s += __shfl_xor(s, 8, 64);
      if ((lane & 15) == 0) atomicAdd(&scores[row], s);
    }
  }
}

// ---------------- softmax over 196 regions: alpha + coverage outputs ----------------
__global__ void softmax_kernel(const float* __restrict__ scores, const float* __restrict__ cov,
                               float* __restrict__ alpha_ws, float* __restrict__ out) {
  const int b = blockIdx.x, tid = threadIdx.x;
  const int lane = tid & 63, wid = tid >> 6;
  __shared__ float red[8];
  float s = (tid < 196) ? scores[b * 196 + tid] : -1e30f;
  float m = s;
  for (int off = 32; off > 0; off >>= 1) m = fmaxf(m, __shfl_xor(m, off, 64));
  if (lane == 0) red[wid] = m;
  __syncthreads();
  m = fmaxf(fmaxf(red[0], red[1]), fmaxf(red[2], red[3]));
  float e = (tid < 196) ? __expf(s - m) : 0.f;
  float t = e;
  for (int off = 32; off > 0; off >>= 1) t += __shfl_xor(t, off, 64);
  if (lane == 0) red[4 + wid] = t;
  __syncthreads();
  const float tot = red[4] + red[5] + red[6] + red[7];
  const float a = e / tot;
  if (tid < 196) {
    alpha_ws[b * 196 + tid] = a;
    out[32768 + b * 196 + tid] = cov[b * 196 + tid] + a;   // coverage_new
    out[32768 + 6272 + b * 196 + tid] = a;                 // alpha_a
  }
}

// ---------------- context: c_img[b, :] = sum_t alpha[b,t] * gstar[b,t,:] ----------------
__global__ __launch_bounds__(256) void ctx_kernel(const float* __restrict__ alpha,
                                                  const float* __restrict__ gstar,
                                                  float* __restrict__ out) {
  const int b = blockIdx.y;
  const int colbase = blockIdx.x * 128;
  const int c = threadIdx.x & 127;
  const int half = threadIdx.x >> 7;     // 0/1 -> rows [0,98) / [98,196)
  const float* g = gstar + ((size_t)b * 196 + half * 98) * 1024 + colbase + c;
  const float* al = alpha + b * 196 + half * 98;
  float acc = 0.f;
#pragma unroll 7
  for (int t = 0; t < 98; ++t) acc += al[t] * g[(size_t)t * 1024];
  __shared__ float part[256];
  part[threadIdx.x] = acc;
  __syncthreads();
  if (threadIdx.x < 128)
    out[b * 1024 + colbase + threadIdx.x] = part[threadIdx.x] + part[threadIdx.x + 128];
}

// ---------------- launch ----------------
extern "C" void kernel_launch(void* const* d_in, const int* in_sizes, int n_in,
                              void* d_out, int out_size, void* d_ws, size_t ws_size,
                              hipStream_t stream) {
  (void)in_sizes; (void)n_in; (void)out_size; (void)ws_size;
  const float* gf   = (const float*)d_in[0];   // [6272, 4096]
  const float* sth  = (const float*)d_in[1];   // [32, 1024]
  const float* cov  = (const float*)d_in[2];   // [6272]
  const float* Wg   = (const float*)d_in[3];   // [4096, 4096]
  const float* bg   = (const float*)d_in[4];   // [4096]
  const float* Gs   = (const float*)d_in[5];   // [4096, 1024]
  const float* bgs  = (const float*)d_in[6];   // [1024]
  const float* Wgs  = (const float*)d_in[7];   // [1024, 1024]
  const float* Wdec = (const float*)d_in[8];   // [1024, 1024]
  const float* bdec = (const float*)d_in[9];   // [1024]
  const float* v    = (const float*)d_in[10];  // [1024]
  float* out = (float*)d_out;

  char* ws = (char*)d_ws;
  // region A [0, 51.4MB):        gf_bf16 ; after GEMM2: alpha (25 KB)
  // region B [51.4MB, 84.9MB):   Wg_bf16 ; after GEMM1: gstar_f32 (25.7 MB)
  // region C [84.9MB, 93.3MB):   GsT_bf16 ; after GEMM1: WgsT_bf16
  // region D [93.3MB, 110.1MB):  C1T_f32 ; after C1T cast consumed -> gstar_bf16
  // region E [110.1MB, 118.5MB): C1T_bf16
  unsigned short* gf_bf   = (unsigned short*)(ws + 0);
  float*          alpha   = (float*)(ws + 0);
  unsigned short* Wg_bf   = (unsigned short*)(ws + 51380224);
  float*          gstar_f = (float*)(ws + 51380224);
  unsigned short* GsT     = (unsigned short*)(ws + 84934656);
  unsigned short* WgsT    = (unsigned short*)(ws + 84934656);
  float*          C1T_f   = (float*)(ws + 93323264);
  unsigned short* gstar_b = (unsigned short*)(ws + 93323264);
  unsigned short* C1T_b   = (unsigned short*)(ws + 110100480);
  float*          bias1   = (float*)(ws + 118489088);
  float*          dec     = (float*)(ws + 118493184);
  float*          scores  = (float*)(ws + 118624256);

  // 1. casts / transposes
  cast_f32_bf16_kernel<<<12544, 256, 0, stream>>>(gf, gf_bf, 3211264);
  cast_f32_bf16_kernel<<<8192, 256, 0, stream>>>(Wg, Wg_bf, 2097152);
  transpose_cast_kernel<<<dim3(32, 128), 256, 0, stream>>>(Gs, GsT, 4096, 1024);
  // 2. bias1 = bg @ Gs + bgs
  init_vec_kernel<<<4, 256, 0, stream>>>(bgs, bias1);
  bias1_accum_kernel<<<dim3(4, 16), 256, 0, stream>>>(bg, Gs, bias1);
  // 3. GEMM1 (split-K=4): C1T[1024,4096] = GsT @ Wg^T
  zero4_kernel<<<4096, 256, 0, stream>>>(C1T_f, 1048576);
  gemm_bt_atomic_kernel<<<dim3(32, 8, 4), 256, 0, stream>>>(GsT, Wg_bf, C1T_f, 1024, 4096, 4096, 1024);
  cast_f32_bf16_kernel<<<2048, 256, 0, stream>>>(C1T_f, C1T_b, 524288);
  // 4. WgsT (region C free after GEMM1)
  transpose_cast_kernel<<<dim3(32, 32), 256, 0, stream>>>(Wgs, WgsT, 1024, 1024);
  // 5. dec_fea = s_t_hat @ Wdec + bdec
  init_dec_kernel<<<128, 256, 0, stream>>>(bdec, dec);
  dec_accum_kernel<<<dim3(4, 8), 256, 0, stream>>>(sth, Wdec, dec);
  // 6. GEMM2 (split-K=2): g_star[6272,1024] = gf @ C1 + bias1  (bias pre-broadcast)
  bcast_bias_kernel<<<6272, 256, 0, stream>>>(bias1, gstar_f);
  gemm_bt_atomic_kernel<<<dim3(8, 49, 2), 256, 0, stream>>>(gf_bf, C1T_b, gstar_f, 6272, 1024, 4096, 2048);
  cast_f32_bf16_kernel<<<3136, 256, 0, stream>>>(gstar_f, gstar_b, 802816);
  // 7. GEMM3 fused with scores epilogue (w_g_star never materialized)
  zero4_kernel<<<7, 256, 0, stream>>>(scores, 1568);
  gemm_scores_kernel<<<dim3(8, 49), 256, 0, stream>>>(gstar_b, WgsT, dec, cov, v, scores, 6272, 1024, 1024);
  // 8. softmax (alpha + coverage outputs), then parallel context
  softmax_kernel<<<32, 256, 0, stream>>>(scores, cov, alpha, out);
  ctx_kernel<<<dim3(8, 32), 256, 0, stream>>>(alpha, gstar_f, out);
}

// Round 3
// 527.808 us; speedup vs baseline: 1.0844x; 1.0844x over previous
//
#include <hip/hip_runtime.h>
#include <hip/hip_bf16.h>

typedef __attribute__((ext_vector_type(8))) short short8;
typedef __attribute__((ext_vector_type(4))) float floatx4;

#define GLOBAL_AS __attribute__((address_space(1)))
#define LDS_AS    __attribute__((address_space(3)))

__device__ __forceinline__ unsigned short f2bf_rne(float x) {
  unsigned int u = __float_as_uint(x);
  u += 0x7fffu + ((u >> 16) & 1u);
  return (unsigned short)(u >> 16);
}

// ---------------- cast fp32 -> bf16 (8 elems/thread) ----------------
__global__ void cast_f32_bf16_kernel(const float* __restrict__ in,
                                     unsigned short* __restrict__ out, int n8) {
  int i = blockIdx.x * 256 + threadIdx.x;
  if (i >= n8) return;
  const float4* p = (const float4*)in;
  float4 v0 = p[2 * i], v1 = p[2 * i + 1];
  short8 o;
  o[0] = (short)f2bf_rne(v0.x); o[1] = (short)f2bf_rne(v0.y);
  o[2] = (short)f2bf_rne(v0.z); o[3] = (short)f2bf_rne(v0.w);
  o[4] = (short)f2bf_rne(v1.x); o[5] = (short)f2bf_rne(v1.y);
  o[6] = (short)f2bf_rne(v1.z); o[7] = (short)f2bf_rne(v1.w);
  *(short8*)(out + 8 * (size_t)i) = o;
}

// ---------------- transpose + cast: in[R][C] fp32 -> out[C][R] bf16 ----------------
__global__ void transpose_cast_kernel(const float* __restrict__ in,
                                      unsigned short* __restrict__ out, int R, int C) {
  __shared__ unsigned short tile[32][33];
  int tx = threadIdx.x & 31, ty = threadIdx.x >> 5;
  int r0 = blockIdx.y * 32, c0 = blockIdx.x * 32;
#pragma unroll
  for (int j = 0; j < 32; j += 8)
    tile[ty + j][tx] = f2bf_rne(in[(size_t)(r0 + ty + j) * C + c0 + tx]);
  __syncthreads();
#pragma unroll
  for (int j = 0; j < 32; j += 8)
    out[(size_t)(c0 + ty + j) * R + r0 + tx] = tile[tx][ty + j];
}

// ---------------- small init / zero kernels ----------------
__global__ void zero4_kernel(float* __restrict__ p, int n4) {
  int i = blockIdx.x * 256 + threadIdx.x;
  if (i < n4) ((float4*)p)[i] = make_float4(0.f, 0.f, 0.f, 0.f);
}
__global__ void init_vec_kernel(const float* __restrict__ src, float* __restrict__ dst) {
  int i = blockIdx.x * 256 + threadIdx.x;
  dst[i] = src[i];
}
__global__ void bias1_accum_kernel(const float* __restrict__ bg, const float* __restrict__ Gs,
                                   float* __restrict__ bias1) {
  int j = blockIdx.x * 256 + threadIdx.x;   // 0..1023
  int k0 = blockIdx.y * 256;
  float acc = 0.f;
  for (int k = 0; k < 256; ++k) acc += bg[k0 + k] * Gs[(size_t)(k0 + k) * 1024 + j];
  atomicAdd(&bias1[j], acc);
}

// ---------------- dec_fea = s_t_hat @ Wdec + bdec (fp32) ----------------
__global__ void init_dec_kernel(const float* __restrict__ bdec, float* __restrict__ dec) {
  int i = blockIdx.x * 256 + threadIdx.x;   // 32768
  dec[i] = bdec[i & 1023];
}
__global__ void dec_accum_kernel(const float* __restrict__ sth, const float* __restrict__ Wdec,
                                 float* __restrict__ dec) {
  __shared__ float ss[32][128];
  const int tid = threadIdx.x;
  const int k0 = blockIdx.y * 128;
  for (int i = tid; i < 32 * 128; i += 256) {
    int bb = i >> 7, kk = i & 127;
    ss[bb][kk] = sth[bb * 1024 + k0 + kk];
  }
  __syncthreads();
  const int j = blockIdx.x * 256 + tid;
  float acc[32];
#pragma unroll
  for (int b = 0; b < 32; ++b) acc[b] = 0.f;
  for (int kk = 0; kk < 128; ++kk) {
    float w = Wdec[(size_t)(k0 + kk) * 1024 + j];
#pragma unroll
    for (int b = 0; b < 32; ++b) acc[b] += ss[b][kk] * w;
  }
  for (int b = 0; b < 32; ++b) atomicAdd(&dec[b * 1024 + j], acc[b]);
}

// ---------------- tiled GEMM: C[M,N] = A[M,K] @ BT[N,K]^T (+bias), BMxBN tile ----------
// 4 waves in 2x2; wave tile (BM/2)x(BN/2). Store-only epilogue: optional fp32 and/or
// bf16 output (fused cast).
template <int BM, int BN, bool HAS_BIAS, bool WRITE_F32, bool WRITE_BF16>
__global__ __launch_bounds__(256, 4) void gemm_tile_kernel(
    const unsigned short* __restrict__ A, const unsigned short* __restrict__ BT,
    const float* __restrict__ bias, float* __restrict__ Cf,
    unsigned short* __restrict__ Cb, int M, int N, int K) {
  constexpr int AF = BM / 32;   // A fragments per wave
  constexpr int BF = BN / 32;   // B fragments per wave
  __shared__ unsigned short lds_a[BM * 32];
  __shared__ unsigned short lds_b[BN * 32];
  const int tid = threadIdx.x;
  const int lane = tid & 63;
  const int wave = tid >> 6;
  const int wm = wave >> 1, wn = wave & 1;
  const int quad = lane >> 4, col = lane & 15;
  const int m0 = blockIdx.y * BM, n0 = blockIdx.x * BN;

  floatx4 acc[AF][BF] = {};

  const int srow = tid >> 2;           // 0..63
  const int skoff = (tid & 3) * 8;     // 0,8,16,24
  const unsigned short* a_ptr = A + (size_t)(m0 + srow) * K + skoff;
  const unsigned short* b_ptr = BT + (size_t)(n0 + srow) * K + skoff;
  const size_t rowskip = (size_t)64 * K;
  char* la_dst = (char*)lds_a + tid * 16;
  char* lb_dst = (char*)lds_b + tid * 16;

  for (int kt = 0; kt < K; kt += 32) {
    __syncthreads();
#pragma unroll
    for (int c = 0; c < BM / 64; ++c)
      __builtin_amdgcn_global_load_lds((const GLOBAL_AS void*)(a_ptr + c * rowskip),
                                       (LDS_AS void*)(la_dst + c * 4096), 16, 0, 0);
#pragma unroll
    for (int c = 0; c < BN / 64; ++c)
      __builtin_amdgcn_global_load_lds((const GLOBAL_AS void*)(b_ptr + c * rowskip),
                                       (LDS_AS void*)(lb_dst + c * 4096), 16, 0, 0);
    a_ptr += 32; b_ptr += 32;
    __syncthreads();
    short8 af[AF], bf[BF];
#pragma unroll
    for (int t = 0; t < AF; ++t)
      af[t] = *(const short8*)((const char*)lds_a + (wm * (BM / 2) + t * 16 + col) * 64 + quad * 16);
#pragma unroll
    for (int t = 0; t < BF; ++t)
      bf[t] = *(const short8*)((const char*)lds_b + (wn * (BN / 2) + t * 16 + col) * 64 + quad * 16);
#pragma unroll
    for (int tm = 0; tm < AF; ++tm)
#pragma unroll
      for (int tn = 0; tn < BF; ++tn)
        acc[tm][tn] = __builtin_amdgcn_mfma_f32_16x16x32_bf16(af[tm], bf[tn], acc[tm][tn], 0, 0, 0);
  }

#pragma unroll
  for (int tm = 0; tm < AF; ++tm) {
    const int mg = m0 + wm * (BM / 2) + tm * 16 + quad * 4;
#pragma unroll
    for (int tn = 0; tn < BF; ++tn) {
      const int ng = n0 + wn * (BN / 2) + tn * 16 + col;
      const float bv = HAS_BIAS ? bias[ng] : 0.0f;
#pragma unroll
      for (int r = 0; r < 4; ++r) {
        const float val = acc[tm][tn][r] + bv;
        if (WRITE_F32) Cf[(size_t)(mg + r) * N + ng] = val;
        if (WRITE_BF16) Cb[(size_t)(mg + r) * N + ng] = f2bf_rne(val);
      }
    }
  }
}

// ---------------- GEMM3 (128x64 tile) fused with scores epilogue ----------------
// scores[row] += sum_{j in 64-col slice} tanh(w + dec + cov) * v[j]; w never stored.
__global__ __launch_bounds__(256, 4) void gemm_scores_kernel(
    const unsigned short* __restrict__ A, const unsigned short* __restrict__ BT,
    const float* __restrict__ dec, const float* __restrict__ cov,
    const float* __restrict__ v, float* __restrict__ scores, int M, int N, int K) {
  __shared__ unsigned short lds_a[128 * 32];
  __shared__ unsigned short lds_b[64 * 32];
  const int tid = threadIdx.x;
  const int lane = tid & 63;
  const int wave = tid >> 6;
  const int wm = wave >> 1, wn = wave & 1;
  const int quad = lane >> 4, col = lane & 15;
  const int m0 = blockIdx.y * 128, n0 = blockIdx.x * 64;

  floatx4 acc[4][2] = {};

  const int srow = tid >> 2;
  const int skoff = (tid & 3) * 8;
  const unsigned short* a_ptr = A + (size_t)(m0 + srow) * K + skoff;
  const unsigned short* b_ptr = BT + (size_t)(n0 + srow) * K + skoff;
  const size_t rowskip = (size_t)64 * K;
  char* la_dst = (char*)lds_a + tid * 16;
  char* lb_dst = (char*)lds_b + tid * 16;

  for (int kt = 0; kt < K; kt += 32) {
    __syncthreads();
    __builtin_amdgcn_global_load_lds((const GLOBAL_AS void*)(a_ptr), (LDS_AS void*)(la_dst), 16, 0, 0);
    __builtin_amdgcn_global_load_lds((const GLOBAL_AS void*)(a_ptr + rowskip), (LDS_AS void*)(la_dst + 4096), 16, 0, 0);
    __builtin_amdgcn_global_load_lds((const GLOBAL_AS void*)(b_ptr), (LDS_AS void*)(lb_dst), 16, 0, 0);
    a_ptr += 32; b_ptr += 32;
    __syncthreads();
    short8 af[4], bf[2];
#pragma unroll
    for (int t = 0; t < 4; ++t)
      af[t] = *(const short8*)((const char*)lds_a + (wm * 64 + t * 16 + col) * 64 + quad * 16);
#pragma unroll
    for (int t = 0; t < 2; ++t)
      bf[t] = *(const short8*)((const char*)lds_b + (wn * 32 + t * 16 + col) * 64 + quad * 16);
#pragma unroll
    for (int tm = 0; tm < 4; ++tm)
#pragma unroll
      for (int tn = 0; tn < 2; ++tn)
        acc[tm][tn] = __builtin_amdgcn_mfma_f32_16x16x32_bf16(af[tm], bf[tn], acc[tm][tn], 0, 0, 0);
  }

  // epilogue: per-row partial tanh-dot over this wave's 32-column slice
  const int n_base = n0 + wn * 32;
  float vv[2];
#pragma unroll
  for (int tn = 0; tn < 2; ++tn) vv[tn] = v[n_base + tn * 16 + col];
#pragma unroll
  for (int tm = 0; tm < 4; ++tm) {
#pragma unroll
    for (int r = 0; r < 4; ++r) {
      const int row = m0 + wm * 64 + tm * 16 + quad * 4 + r;
      const int b = row / 196;
      const float cw = cov[row];
      const float* dr = dec + b * 1024 + n_base;
      float s = 0.f;
#pragma unroll
      for (int tn = 0; tn < 2; ++tn)
        s += tanhf(acc[tm][tn][r] + dr[tn * 16 + col] + cw) * vv[tn];
      s += __shfl_xor(s, 1, 64);
      s += __shfl_xor(s, 2, 64);
      s += __shfl_xor(s, 4, 64);
      s += __shfl_xor(s, 8, 64);
      if ((lane & 15) == 0) atomicAdd(&scores[row], s);
    }
  }
}

// ---------------- softmax over 196 regions: alpha + coverage outputs ----------------
__global__ void softmax_kernel(const float* __restrict__ scores, const float* __restrict__ cov,
                               float* __restrict__ alpha_ws, float* __restrict__ out) {
  const int b = blockIdx.x, tid = threadIdx.x;
  const int lane = tid & 63, wid = tid >> 6;
  __shared__ float red[8];
  float s = (tid < 196) ? scores[b * 196 + tid] : -1e30f;
  float m = s;
  for (int off = 32; off > 0; off >>= 1) m = fmaxf(m, __shfl_xor(m, off, 64));
  if (lane == 0) red[wid] = m;
  __syncthreads();
  m = fmaxf(fmaxf(red[0], red[1]), fmaxf(red[2], red[3]));
  float e = (tid < 196) ? __expf(s - m) : 0.f;
  float t = e;
  for (int off = 32; off > 0; off >>= 1) t += __shfl_xor(t, off, 64);
  if (lane == 0) red[4 + wid] = t;
  __syncthreads();
  const float tot = red[4] + red[5] + red[6] + red[7];
  const float a = e / tot;
  if (tid < 196) {
    alpha_ws[b * 196 + tid] = a;
    out[32768 + b * 196 + tid] = cov[b * 196 + tid] + a;   // coverage_new
    out[32768 + 6272 + b * 196 + tid] = a;                 // alpha_a
  }
}

// ---------------- context: c_img[b, :] = sum_t alpha[b,t] * gstar[b,t,:] ----------------
__global__ __launch_bounds__(256) void ctx_kernel(const float* __restrict__ alpha,
                                                  const float* __restrict__ gstar,
                                                  float* __restrict__ out) {
  const int b = blockIdx.y;
  const int colbase = blockIdx.x * 128;
  const int c = threadIdx.x & 127;
  const int half = threadIdx.x >> 7;     // 0/1 -> rows [0,98) / [98,196)
  const float* g = gstar + ((size_t)b * 196 + half * 98) * 1024 + colbase + c;
  const float* al = alpha + b * 196 + half * 98;
  float acc = 0.f;
#pragma unroll 7
  for (int t = 0; t < 98; ++t) acc += al[t] * g[(size_t)t * 1024];
  __shared__ float part[256];
  part[threadIdx.x] = acc;
  __syncthreads();
  if (threadIdx.x < 128)
    out[b * 1024 + colbase + threadIdx.x] = part[threadIdx.x] + part[threadIdx.x + 128];
}

// ---------------- launch ----------------
extern "C" void kernel_launch(void* const* d_in, const int* in_sizes, int n_in,
                              void* d_out, int out_size, void* d_ws, size_t ws_size,
                              hipStream_t stream) {
  (void)in_sizes; (void)n_in; (void)out_size; (void)ws_size;
  const float* gf   = (const float*)d_in[0];   // [6272, 4096]
  const float* sth  = (const float*)d_in[1];   // [32, 1024]
  const float* cov  = (const float*)d_in[2];   // [6272]
  const float* Wg   = (const float*)d_in[3];   // [4096, 4096]
  const float* bg   = (const float*)d_in[4];   // [4096]
  const float* Gs   = (const float*)d_in[5];   // [4096, 1024]
  const float* bgs  = (const float*)d_in[6];   // [1024]
  const float* Wgs  = (const float*)d_in[7];   // [1024, 1024]
  const float* Wdec = (const float*)d_in[8];   // [1024, 1024]
  const float* bdec = (const float*)d_in[9];   // [1024]
  const float* v    = (const float*)d_in[10];  // [1024]
  float* out = (float*)d_out;

  char* ws = (char*)d_ws;
  // region A [0, 51.4MB):          gf_bf16 ; after GEMM2+3: alpha (25 KB)
  // region B [51.4MB, 84.9MB):     Wg_bf16 ; after GEMM1: gstar_f32 (25.7 MB)
  // region C [84.9MB, 93.3MB):     GsT_bf16 ; after GEMM1: WgsT_bf16
  // region D [93.3MB, 101.7MB):    C1T_bf16 (written directly by GEMM1)
  // region E [101.7MB, 114.6MB):   gstar_bf16 (written by GEMM2 epilogue)
  unsigned short* gf_bf   = (unsigned short*)(ws + 0);
  float*          alpha   = (float*)(ws + 0);
  unsigned short* Wg_bf   = (unsigned short*)(ws + 51380224);
  float*          gstar_f = (float*)(ws + 51380224);
  unsigned short* GsT     = (unsigned short*)(ws + 84934656);
  unsigned short* WgsT    = (unsigned short*)(ws + 84934656);
  unsigned short* C1T_b   = (unsigned short*)(ws + 93323264);
  unsigned short* gstar_b = (unsigned short*)(ws + 101711872);
  float*          bias1   = (float*)(ws + 114556928);
  float*          dec     = (float*)(ws + 114561024);
  float*          scores  = (float*)(ws + 114692096);

  // 1. casts / transposes
  cast_f32_bf16_kernel<<<12544, 256, 0, stream>>>(gf, gf_bf, 3211264);
  cast_f32_bf16_kernel<<<8192, 256, 0, stream>>>(Wg, Wg_bf, 2097152);
  transpose_cast_kernel<<<dim3(32, 128), 256, 0, stream>>>(Gs, GsT, 4096, 1024);
  // 2. bias1 = bg @ Gs + bgs
  init_vec_kernel<<<4, 256, 0, stream>>>(bgs, bias1);
  bias1_accum_kernel<<<dim3(4, 16), 256, 0, stream>>>(bg, Gs, bias1);
  // 3. GEMM1: C1T[1024,4096] = GsT @ Wg^T, bf16 out directly. 128x64 tiles -> 512 blocks.
  gemm_tile_kernel<128, 64, false, false, true><<<dim3(64, 8), 256, 0, stream>>>(
      GsT, Wg_bf, nullptr, nullptr, C1T_b, 1024, 4096, 4096);
  // 4. WgsT (region C free after GEMM1)
  transpose_cast_kernel<<<dim3(32, 32), 256, 0, stream>>>(Wgs, WgsT, 1024, 1024);
  // 5. dec_fea = s_t_hat @ Wdec + bdec
  init_dec_kernel<<<128, 256, 0, stream>>>(bdec, dec);
  dec_accum_kernel<<<dim3(4, 8), 256, 0, stream>>>(sth, Wdec, dec);
  // 6. GEMM2: g_star[6272,1024] = gf @ C1 + bias1; writes fp32 AND bf16 (fused cast).
  //    128x64 tiles -> 784 blocks.
  gemm_tile_kernel<128, 64, true, true, true><<<dim3(16, 49), 256, 0, stream>>>(
      gf_bf, C1T_b, bias1, gstar_f, gstar_b, 6272, 1024, 4096);
  // 7. GEMM3 fused with scores epilogue (w_g_star never materialized). 784 blocks.
  zero4_kernel<<<2, 256, 0, stream>>>(scores, 392);
  gemm_scores_kernel<<<dim3(16, 49), 256, 0, stream>>>(
      gstar_b, WgsT, dec, cov, v, scores, 6272, 1024, 1024);
  // 8. softmax (alpha + coverage outputs), then parallel context
  softmax_kernel<<<32, 256, 0, stream>>>(scores, cov, alpha, out);
  ctx_kernel<<<dim3(8, 32), 256, 0, stream>>>(alpha, gstar_f, out);
}

// Round 5
// 502.989 us; speedup vs baseline: 1.1379x; 1.0493x over previous
//
#include <hip/hip_runtime.h>
#include <hip/hip_bf16.h>

typedef __attribute__((ext_vector_type(8))) short short8;
typedef __attribute__((ext_vector_type(4))) float floatx4;

#define GLOBAL_AS __attribute__((address_space(1)))
#define LDS_AS    __attribute__((address_space(3)))

__device__ __forceinline__ unsigned short f2bf_rne(float x) {
  unsigned int u = __float_as_uint(x);
  u += 0x7fffu + ((u >> 16) & 1u);
  return (unsigned short)(u >> 16);
}

// ---------------- cast fp32 -> bf16 (8 elems/thread) ----------------
__global__ void cast_f32_bf16_kernel(const float* __restrict__ in,
                                     unsigned short* __restrict__ out, int n8) {
  int i = blockIdx.x * 256 + threadIdx.x;
  if (i >= n8) return;
  const float4* p = (const float4*)in;
  float4 v0 = p[2 * i], v1 = p[2 * i + 1];
  short8 o;
  o[0] = (short)f2bf_rne(v0.x); o[1] = (short)f2bf_rne(v0.y);
  o[2] = (short)f2bf_rne(v0.z); o[3] = (short)f2bf_rne(v0.w);
  o[4] = (short)f2bf_rne(v1.x); o[5] = (short)f2bf_rne(v1.y);
  o[6] = (short)f2bf_rne(v1.z); o[7] = (short)f2bf_rne(v1.w);
  *(short8*)(out + 8 * (size_t)i) = o;
}

// ---------------- transpose + cast: in[R][C] fp32 -> out[C][R] bf16 ----------------
__global__ void transpose_cast_kernel(const float* __restrict__ in,
                                      unsigned short* __restrict__ out, int R, int C) {
  __shared__ unsigned short tile[32][33];
  int tx = threadIdx.x & 31, ty = threadIdx.x >> 5;
  int r0 = blockIdx.y * 32, c0 = blockIdx.x * 32;
#pragma unroll
  for (int j = 0; j < 32; j += 8)
    tile[ty + j][tx] = f2bf_rne(in[(size_t)(r0 + ty + j) * C + c0 + tx]);
  __syncthreads();
#pragma unroll
  for (int j = 0; j < 32; j += 8)
    out[(size_t)(c0 + ty + j) * R + r0 + tx] = tile[tx][ty + j];
}

// ---------------- small init / zero kernels ----------------
__global__ void zero4_kernel(float* __restrict__ p, int n4) {
  int i = blockIdx.x * 256 + threadIdx.x;
  if (i < n4) ((float4*)p)[i] = make_float4(0.f, 0.f, 0.f, 0.f);
}
__global__ void init_vec_kernel(const float* __restrict__ src, float* __restrict__ dst) {
  int i = blockIdx.x * 256 + threadIdx.x;
  dst[i] = src[i];
}
__global__ void bias1_accum_kernel(const float* __restrict__ bg, const float* __restrict__ Gs,
                                   float* __restrict__ bias1) {
  int j = blockIdx.x * 256 + threadIdx.x;   // 0..1023
  int k0 = blockIdx.y * 256;
  float acc = 0.f;
  for (int k = 0; k < 256; ++k) acc += bg[k0 + k] * Gs[(size_t)(k0 + k) * 1024 + j];
  atomicAdd(&bias1[j], acc);
}

// ---------------- dec_fea = s_t_hat @ Wdec + bdec (fp32) ----------------
__global__ void init_dec_kernel(const float* __restrict__ bdec, float* __restrict__ dec) {
  int i = blockIdx.x * 256 + threadIdx.x;   // 32768
  dec[i] = bdec[i & 1023];
}
__global__ void dec_accum_kernel(const float* __restrict__ sth, const float* __restrict__ Wdec,
                                 float* __restrict__ dec) {
  __shared__ float ss[32][128];
  const int tid = threadIdx.x;
  const int k0 = blockIdx.y * 128;
  for (int i = tid; i < 32 * 128; i += 256) {
    int bb = i >> 7, kk = i & 127;
    ss[bb][kk] = sth[bb * 1024 + k0 + kk];
  }
  __syncthreads();
  const int j = blockIdx.x * 256 + tid;
  float acc[32];
#pragma unroll
  for (int b = 0; b < 32; ++b) acc[b] = 0.f;
  for (int kk = 0; kk < 128; ++kk) {
    float w = Wdec[(size_t)(k0 + kk) * 1024 + j];
#pragma unroll
    for (int b = 0; b < 32; ++b) acc[b] += ss[b][kk] * w;
  }
  for (int b = 0; b < 32; ++b) atomicAdd(&dec[b * 1024 + j], acc[b]);
}

// ---------------- tiled GEMM, BK=64 (two 32-k slabs): C = A @ BT^T (+bias) ----------
// LDS per operand: 2 slabs of [tile][32] bf16, 64-B row stride (m97 geometry preserved
// per slab -> wave-uniform global_load_lds contiguity + 2-way-free bank pattern).
// Slab byte size: rows*64 (ASLAB/BSLAB) — half of the declared array.
template <int BM, int BN, bool HAS_BIAS, bool WRITE_F32, bool WRITE_BF16>
__global__ __launch_bounds__(256, 4) void gemm_tile_kernel(
    const unsigned short* __restrict__ A, const unsigned short* __restrict__ BT,
    const float* __restrict__ bias, float* __restrict__ Cf,
    unsigned short* __restrict__ Cb, int M, int N, int K) {
  constexpr int AF = BM / 32;        // A fragments per wave (half-tile / 16)
  constexpr int BF = BN / 32;        // B fragments per wave
  constexpr int ASLAB = BM * 64;     // BYTES per A k-slab (BM rows x 64B)
  constexpr int BSLAB = BN * 64;     // BYTES per B k-slab
  __shared__ unsigned short lds_a[BM * 64];   // 2 slabs of BM*32 shorts
  __shared__ unsigned short lds_b[BN * 64];
  const int tid = threadIdx.x;
  const int lane = tid & 63;
  const int wave = tid >> 6;
  const int wm = wave >> 1, wn = wave & 1;
  const int quad = lane >> 4, col = lane & 15;
  const int m0 = blockIdx.y * BM, n0 = blockIdx.x * BN;

  floatx4 acc[AF][BF] = {};

  const int srow = tid >> 2;           // 0..63
  const int skoff = (tid & 3) * 8;     // 0,8,16,24
  const unsigned short* a_ptr = A + (size_t)(m0 + srow) * K + skoff;
  const unsigned short* b_ptr = BT + (size_t)(n0 + srow) * K + skoff;
  const size_t rowskip = (size_t)64 * K;
  char* la_dst = (char*)lds_a + tid * 16;
  char* lb_dst = (char*)lds_b + tid * 16;

  for (int kt = 0; kt < K; kt += 64) {
    __syncthreads();
#pragma unroll
    for (int h = 0; h < BM / 64; ++h)
#pragma unroll
      for (int s = 0; s < 2; ++s)
        __builtin_amdgcn_global_load_lds((const GLOBAL_AS void*)(a_ptr + h * rowskip + s * 32),
                                         (LDS_AS void*)(la_dst + s * ASLAB + h * 4096), 16, 0, 0);
#pragma unroll
    for (int h = 0; h < BN / 64; ++h)
#pragma unroll
      for (int s = 0; s < 2; ++s)
        __builtin_amdgcn_global_load_lds((const GLOBAL_AS void*)(b_ptr + h * rowskip + s * 32),
                                         (LDS_AS void*)(lb_dst + s * BSLAB + h * 4096), 16, 0, 0);
    a_ptr += 64; b_ptr += 64;
    __syncthreads();
#pragma unroll
    for (int s = 0; s < 2; ++s) {
      short8 af[AF], bf[BF];
#pragma unroll
      for (int t = 0; t < AF; ++t)
        af[t] = *(const short8*)((const char*)lds_a + s * ASLAB +
                                 (wm * (BM / 2) + t * 16 + col) * 64 + quad * 16);
#pragma unroll
      for (int t = 0; t < BF; ++t)
        bf[t] = *(const short8*)((const char*)lds_b + s * BSLAB +
                                 (wn * (BN / 2) + t * 16 + col) * 64 + quad * 16);
#pragma unroll
      for (int tm = 0; tm < AF; ++tm)
#pragma unroll
        for (int tn = 0; tn < BF; ++tn)
          acc[tm][tn] = __builtin_amdgcn_mfma_f32_16x16x32_bf16(af[tm], bf[tn], acc[tm][tn], 0, 0, 0);
    }
  }

#pragma unroll
  for (int tm = 0; tm < AF; ++tm) {
    const int mg = m0 + wm * (BM / 2) + tm * 16 + quad * 4;
#pragma unroll
    for (int tn = 0; tn < BF; ++tn) {
      const int ng = n0 + wn * (BN / 2) + tn * 16 + col;
      const float bv = HAS_BIAS ? bias[ng] : 0.0f;
#pragma unroll
      for (int r = 0; r < 4; ++r) {
        const float val = acc[tm][tn][r] + bv;
        if (WRITE_F32) Cf[(size_t)(mg + r) * N + ng] = val;
        if (WRITE_BF16) Cb[(size_t)(mg + r) * N + ng] = f2bf_rne(val);
      }
    }
  }
}

// ---------------- GEMM3 (128x64 tile, BK=64) fused with scores epilogue ----------------
// scores[row] += sum_{j in 64-col slice} tanh(w + dec + cov) * v[j]; w never stored.
// Slab strides: A slab = 8192 B (128 rows x 64B), B slab = 4096 B (64 rows x 64B).
__global__ __launch_bounds__(256, 4) void gemm_scores_kernel(
    const unsigned short* __restrict__ A, const unsigned short* __restrict__ BT,
    const float* __restrict__ dec, const float* __restrict__ cov,
    const float* __restrict__ v, float* __restrict__ scores, int M, int N, int K) {
  __shared__ unsigned short lds_a[128 * 64];   // 2 slabs of [128][32] -> 8192 B each
  __shared__ unsigned short lds_b[64 * 64];    // 2 slabs of [64][32]  -> 4096 B each
  const int tid = threadIdx.x;
  const int lane = tid & 63;
  const int wave = tid >> 6;
  const int wm = wave >> 1, wn = wave & 1;
  const int quad = lane >> 4, col = lane & 15;
  const int m0 = blockIdx.y * 128, n0 = blockIdx.x * 64;

  floatx4 acc[4][2] = {};

  const int srow = tid >> 2;
  const int skoff = (tid & 3) * 8;
  const unsigned short* a_ptr = A + (size_t)(m0 + srow) * K + skoff;
  const unsigned short* b_ptr = BT + (size_t)(n0 + srow) * K + skoff;
  const size_t rowskip = (size_t)64 * K;
  char* la_dst = (char*)lds_a + tid * 16;
  char* lb_dst = (char*)lds_b + tid * 16;

  for (int kt = 0; kt < K; kt += 64) {
    __syncthreads();
#pragma unroll
    for (int h = 0; h < 2; ++h)
#pragma unroll
      for (int s = 0; s < 2; ++s)
        __builtin_amdgcn_global_load_lds((const GLOBAL_AS void*)(a_ptr + h * rowskip + s * 32),
                                         (LDS_AS void*)(la_dst + s * 8192 + h * 4096), 16, 0, 0);
#pragma unroll
    for (int s = 0; s < 2; ++s)
      __builtin_amdgcn_global_load_lds((const GLOBAL_AS void*)(b_ptr + s * 32),
                                       (LDS_AS void*)(lb_dst + s * 4096), 16, 0, 0);
    a_ptr += 64; b_ptr += 64;
    __syncthreads();
#pragma unroll
    for (int s = 0; s < 2; ++s) {
      short8 af[4], bf[2];
#pragma unroll
      for (int t = 0; t < 4; ++t)
        af[t] = *(const short8*)((const char*)lds_a + s * 8192 +
                                 (wm * 64 + t * 16 + col) * 64 + quad * 16);
#pragma unroll
      for (int t = 0; t < 2; ++t)
        bf[t] = *(const short8*)((const char*)lds_b + s * 4096 +
                                 (wn * 32 + t * 16 + col) * 64 + quad * 16);
#pragma unroll
      for (int tm = 0; tm < 4; ++tm)
#pragma unroll
        for (int tn = 0; tn < 2; ++tn)
          acc[tm][tn] = __builtin_amdgcn_mfma_f32_16x16x32_bf16(af[tm], bf[tn], acc[tm][tn], 0, 0, 0);
    }
  }

  // epilogue: per-row partial tanh-dot over this wave's 32-column slice
  const int n_base = n0 + wn * 32;
  float vv[2];
#pragma unroll
  for (int tn = 0; tn < 2; ++tn) vv[tn] = v[n_base + tn * 16 + col];
#pragma unroll
  for (int tm = 0; tm < 4; ++tm) {
#pragma unroll
    for (int r = 0; r < 4; ++r) {
      const int row = m0 + wm * 64 + tm * 16 + quad * 4 + r;
      const int b = row / 196;
      const float cw = cov[row];
      const float* dr = dec + b * 1024 + n_base;
      float s = 0.f;
#pragma unroll
      for (int tn = 0; tn < 2; ++tn)
        s += tanhf(acc[tm][tn][r] + dr[tn * 16 + col] + cw) * vv[tn];
      s += __shfl_xor(s, 1, 64);
      s += __shfl_xor(s, 2, 64);
      s += __shfl_xor(s, 4, 64);
      s += __shfl_xor(s, 8, 64);
      if ((lane & 15) == 0) atomicAdd(&scores[row], s);
    }
  }
}

// ---------------- softmax over 196 regions: alpha + coverage outputs ----------------
__global__ void softmax_kernel(const float* __restrict__ scores, const float* __restrict__ cov,
                               float* __restrict__ alpha_ws, float* __restrict__ out) {
  const int b = blockIdx.x, tid = threadIdx.x;
  const int lane = tid & 63, wid = tid >> 6;
  __shared__ float red[8];
  float s = (tid < 196) ? scores[b * 196 + tid] : -1e30f;
  float m = s;
  for (int off = 32; off > 0; off >>= 1) m = fmaxf(m, __shfl_xor(m, off, 64));
  if (lane == 0) red[wid] = m;
  __syncthreads();
  m = fmaxf(fmaxf(red[0], red[1]), fmaxf(red[2], red[3]));
  float e = (tid < 196) ? __expf(s - m) : 0.f;
  float t = e;
  for (int off = 32; off > 0; off >>= 1) t += __shfl_xor(t, off, 64);
  if (lane == 0) red[4 + wid] = t;
  __syncthreads();
  const float tot = red[4] + red[5] + red[6] + red[7];
  const float a = e / tot;
  if (tid < 196) {
    alpha_ws[b * 196 + tid] = a;
    out[32768 + b * 196 + tid] = cov[b * 196 + tid] + a;   // coverage_new
    out[32768 + 6272 + b * 196 + tid] = a;                 // alpha_a
  }
}

// ---------------- context: c_img[b, :] = sum_t alpha[b,t] * gstar[b,t,:] ----------------
__global__ __launch_bounds__(256) void ctx_kernel(const float* __restrict__ alpha,
                                                  const float* __restrict__ gstar,
                                                  float* __restrict__ out) {
  const int b = blockIdx.y;
  const int colbase = blockIdx.x * 128;
  const int c = threadIdx.x & 127;
  const int half = threadIdx.x >> 7;     // 0/1 -> rows [0,98) / [98,196)
  const float* g = gstar + ((size_t)b * 196 + half * 98) * 1024 + colbase + c;
  const float* al = alpha + b * 196 + half * 98;
  float acc = 0.f;
#pragma unroll 7
  for (int t = 0; t < 98; ++t) acc += al[t] * g[(size_t)t * 1024];
  __shared__ float part[256];
  part[threadIdx.x] = acc;
  __syncthreads();
  if (threadIdx.x < 128)
    out[b * 1024 + colbase + threadIdx.x] = part[threadIdx.x] + part[threadIdx.x + 128];
}

// ---------------- launch ----------------
extern "C" void kernel_launch(void* const* d_in, const int* in_sizes, int n_in,
                              void* d_out, int out_size, void* d_ws, size_t ws_size,
                              hipStream_t stream) {
  (void)in_sizes; (void)n_in; (void)out_size; (void)ws_size;
  const float* gf   = (const float*)d_in[0];   // [6272, 4096]
  const float* sth  = (const float*)d_in[1];   // [32, 1024]
  const float* cov  = (const float*)d_in[2];   // [6272]
  const float* Wg   = (const float*)d_in[3];   // [4096, 4096]
  const float* bg   = (const float*)d_in[4];   // [4096]
  const float* Gs   = (const float*)d_in[5];   // [4096, 1024]
  const float* bgs  = (const float*)d_in[6];   // [1024]
  const float* Wgs  = (const float*)d_in[7];   // [1024, 1024]
  const float* Wdec = (const float*)d_in[8];   // [1024, 1024]
  const float* bdec = (const float*)d_in[9];   // [1024]
  const float* v    = (const float*)d_in[10];  // [1024]
  float* out = (float*)d_out;

  char* ws = (char*)d_ws;
  // region A [0, 51.4MB):          gf_bf16 ; after GEMM2+3: alpha (25 KB)
  // region B [51.4MB, 84.9MB):     Wg_bf16 ; after GEMM1: gstar_f32 (25.7 MB)
  // region C [84.9MB, 93.3MB):     GsT_bf16 ; after GEMM1: WgsT_bf16
  // region D [93.3MB, 101.7MB):    C1T_bf16 (written directly by GEMM1)
  // region E [101.7MB, 114.6MB):   gstar_bf16 (written by GEMM2 epilogue)
  unsigned short* gf_bf   = (unsigned short*)(ws + 0);
  float*          alpha   = (float*)(ws + 0);
  unsigned short* Wg_bf   = (unsigned short*)(ws + 51380224);
  float*          gstar_f = (float*)(ws + 51380224);
  unsigned short* GsT     = (unsigned short*)(ws + 84934656);
  unsigned short* WgsT    = (unsigned short*)(ws + 84934656);
  unsigned short* C1T_b   = (unsigned short*)(ws + 93323264);
  unsigned short* gstar_b = (unsigned short*)(ws + 101711872);
  float*          bias1   = (float*)(ws + 114556928);
  float*          dec     = (float*)(ws + 114561024);
  float*          scores  = (float*)(ws + 114692096);

  // 1. casts / transposes
  cast_f32_bf16_kernel<<<12544, 256, 0, stream>>>(gf, gf_bf, 3211264);
  cast_f32_bf16_kernel<<<8192, 256, 0, stream>>>(Wg, Wg_bf, 2097152);
  transpose_cast_kernel<<<dim3(32, 128), 256, 0, stream>>>(Gs, GsT, 4096, 1024);
  // 2. bias1 = bg @ Gs + bgs
  init_vec_kernel<<<4, 256, 0, stream>>>(bgs, bias1);
  bias1_accum_kernel<<<dim3(4, 16), 256, 0, stream>>>(bg, Gs, bias1);
  // 3. GEMM1: C1T[1024,4096] = GsT @ Wg^T, bf16 out directly. 128x64 tiles -> 512 blocks.
  gemm_tile_kernel<128, 64, false, false, true><<<dim3(64, 8), 256, 0, stream>>>(
      GsT, Wg_bf, nullptr, nullptr, C1T_b, 1024, 4096, 4096);
  // 4. WgsT (region C free after GEMM1)
  transpose_cast_kernel<<<dim3(32, 32), 256, 0, stream>>>(Wgs, WgsT, 1024, 1024);
  // 5. dec_fea = s_t_hat @ Wdec + bdec
  init_dec_kernel<<<128, 256, 0, stream>>>(bdec, dec);
  dec_accum_kernel<<<dim3(4, 8), 256, 0, stream>>>(sth, Wdec, dec);
  // 6. GEMM2: g_star[6272,1024] = gf @ C1 + bias1; writes fp32 AND bf16 (fused cast).
  gemm_tile_kernel<128, 64, true, true, true><<<dim3(16, 49), 256, 0, stream>>>(
      gf_bf, C1T_b, bias1, gstar_f, gstar_b, 6272, 1024, 4096);
  // 7. GEMM3 fused with scores epilogue (w_g_star never materialized). 784 blocks.
  zero4_kernel<<<2, 256, 0, stream>>>(scores, 392);
  gemm_scores_kernel<<<dim3(16, 49), 256, 0, stream>>>(
      gstar_b, WgsT, dec, cov, v, scores, 6272, 1024, 1024);
  // 8. softmax (alpha + coverage outputs), then parallel context
  softmax_kernel<<<32, 256, 0, stream>>>(scores, cov, alpha, out);
  ctx_kernel<<<dim3(8, 32), 256, 0, stream>>>(alpha, gstar_f, out);
}